// Round 10
// baseline (190.800 us; speedup 1.0000x reference)
//
#include <hip/hip_runtime.h>
#include <hip/hip_bf16.h>

// MultiHeadAttention: B=2, S=2048, E=1024, H=16, d=64
// bf16 MFMA (16x16x32) everywhere; fp32 softmax.
// R10: attn is LDS-pipe-bound (per-R9 cycle model: 56us of DS traffic vs
// 4.6us MFMA). Fix: 32 queries/wave (2 query groups) so every K/V b128
// fragment read feeds TWO MFMAs -> per-query LDS cost drops 1.7x.
// 128q/256thr blocks, grid 512 = 2 blocks/CU, 48KB LDS, dbuf 64-key tiles.

#define E_DIM   1024
#define NHEADS  16
#define HDIM    64
#define SEQ     2048
#define TOK     4096          // B*S
#define QKV_DIM 3072
#define QK_STRIDE 2048        // compacted Q|K per-token row
#define QSCALE_F 0.18033688011112042f   // 0.125 * log2(e)

typedef __attribute__((ext_vector_type(8))) short bf16x8;   // 8 bf16 = 4 VGPRs
typedef __attribute__((ext_vector_type(4))) float f32x4;
typedef __attribute__((ext_vector_type(4))) int   i32x4;
typedef __attribute__((ext_vector_type(2))) int   i32x2;
typedef __attribute__((ext_vector_type(2))) __bf16 bf16x2_t;

#if __has_builtin(__builtin_amdgcn_exp2f)
#define EXP2F(x) __builtin_amdgcn_exp2f(x)
#else
#define EXP2F(x) exp2f(x)
#endif

__device__ __forceinline__ unsigned pack2bf(float a, float b) {
#if __has_builtin(__builtin_amdgcn_cvt_pk_bf16_f32)
    union { bf16x2_t v; unsigned u; } u;
    u.v = __builtin_amdgcn_cvt_pk_bf16_f32(a, b);
    return u.u;
#else
    union { float f; unsigned u; } ua, ub; ua.f = a; ub.f = b;
    unsigned ra = ua.u + 0x7FFF + ((ua.u >> 16) & 1);
    unsigned rb = ub.u + 0x7FFF + ((ub.u >> 16) & 1);
    return (ra >> 16) | (rb & 0xFFFF0000u);
#endif
}

__device__ __forceinline__ unsigned short f2bf(float x) {   // 1 VALU op
    return (unsigned short)(pack2bf(x, x) & 0xFFFFu);
}

__device__ __forceinline__ void load_lds16(const void* g, void* l) {
    __builtin_amdgcn_global_load_lds(
        (const __attribute__((address_space(1))) void*)g,
        (__attribute__((address_space(3))) void*)l, 16, 0, 0);
}

__device__ __forceinline__ bf16x8 lds_read8(const unsigned short* p) {
    union { i32x4 i; bf16x8 b; } u;
    u.i = *(const i32x4*)p;   // ds_read_b128
    return u.b;
}

__device__ __forceinline__ f32x4 mfma16(bf16x8 a, bf16x8 b, f32x4 c) {
    return __builtin_amdgcn_mfma_f32_16x16x32_bf16(a, b, c, 0, 0, 0);
}

// ---------------------------------------------------------------- fused casts
__global__ void cast3_kernel(const float* __restrict__ a, unsigned short* __restrict__ oa, int na4,
                             const float* __restrict__ b, unsigned short* __restrict__ ob, int nb4,
                             const float* __restrict__ c, unsigned short* __restrict__ oc) {
    int i = blockIdx.x * blockDim.x + threadIdx.x;
    const float* src; unsigned short* dst; int j;
    if (i < na4)            { src = a; dst = oa; j = i; }
    else if (i < na4 + nb4) { src = b; dst = ob; j = i - na4; }
    else                    { src = c; dst = oc; j = i - na4 - nb4; }
    f32x4 v = ((const f32x4*)src)[j];
    union { i32x2 i2; unsigned u[2]; } o;
    o.u[0] = pack2bf(v.x, v.y);
    o.u[1] = pack2bf(v.z, v.w);
    ((i32x2*)dst)[j] = o.i2;
}

// ---------------------------------------------------------------- GEMM1 (QKV)
// [4096,3072] = x[4096,1024] @ qkv_w^T + qkv_b, fused output routing:
//   col%192 <  64 (Q): *QSCALE -> qk[row*2048 + h*128 + part]
//   col%192 < 128 (K):          -> qk[row*2048 + h*128 + part]
//   col%192 >= 128 (V):         -> vT[((b*16+h)*64 + part-128)*2048 + s]
__global__ __launch_bounds__(256, 3)
void gemm_qkv_kernel(const unsigned short* __restrict__ A,
                     const unsigned short* __restrict__ B,
                     const float* __restrict__ bias,
                     unsigned short* __restrict__ qk,
                     unsigned short* __restrict__ vT,
                     int K) {
    __shared__ __align__(16) unsigned short As[128 * 64];
    __shared__ __align__(16) unsigned short Bs[128 * 64];

    const int tid  = threadIdx.x;
    const int wave = tid >> 6, lane = tid & 63;
    const int quad = lane >> 4, l16 = lane & 15;
    const int row0 = blockIdx.y * 128, col0 = blockIdx.x * 128;
    const int wr = (wave >> 1) * 64, wc = (wave & 1) * 64;

    f32x4 acc[4][4];
#pragma unroll
    for (int i = 0; i < 4; ++i)
#pragma unroll
        for (int j = 0; j < 4; ++j) acc[i][j] = (f32x4){0.f, 0.f, 0.f, 0.f};

    const int nkt = K >> 6;
    for (int kt = 0; kt < nkt; ++kt) {
        const int k0 = kt << 6;
#pragma unroll
        for (int i = 0; i < 4; ++i) {
            int p = i * 256 + tid;
            int r = p >> 3;
            int kc = (p & 7) ^ (r & 7);
            load_lds16(A + (size_t)(row0 + r) * K + k0 + kc * 8, &As[p * 8]);
        }
#pragma unroll
        for (int i = 0; i < 4; ++i) {
            int p = i * 256 + tid;
            int r = p >> 3;
            int kc = (p & 7) ^ (r & 7);
            load_lds16(B + (size_t)(col0 + r) * K + k0 + kc * 8, &Bs[p * 8]);
        }
        __syncthreads();

#pragma unroll
        for (int ks = 0; ks < 2; ++ks) {
            bf16x8 af[4], bfr[4];
#pragma unroll
            for (int rb = 0; rb < 4; ++rb) {
                int r_l  = wr + rb * 16 + l16;
                int phys = (ks * 4 + quad) ^ (l16 & 7);
                af[rb] = lds_read8(&As[r_l * 64 + phys * 8]);
            }
#pragma unroll
            for (int cb = 0; cb < 4; ++cb) {
                int r_l  = wc + cb * 16 + l16;
                int phys = (ks * 4 + quad) ^ (l16 & 7);
                bfr[cb] = lds_read8(&Bs[r_l * 64 + phys * 8]);
            }
#pragma unroll
            for (int rb = 0; rb < 4; ++rb)
#pragma unroll
                for (int cb = 0; cb < 4; ++cb)
                    acc[rb][cb] = mfma16(af[rb], bfr[cb], acc[rb][cb]);
        }
        __syncthreads();
    }

    // epilogue: C row = quad*4+reg, col = l16 (m89/m91 layout)
#pragma unroll
    for (int rb = 0; rb < 4; ++rb)
#pragma unroll
        for (int cb = 0; cb < 4; ++cb) {
            int col = col0 + wc + cb * 16 + l16;
            int h    = col / 192;
            int part = col - h * 192;
            float bv = bias[col];
            int row_b = row0 + wr + rb * 16 + quad * 4;
            float v[4];
#pragma unroll
            for (int reg = 0; reg < 4; ++reg) v[reg] = acc[rb][cb][reg] + bv;
            if (part < 128) {                  // Q or K -> qk row-major
                float sc = (part < 64) ? QSCALE_F : 1.0f;
                size_t base = (size_t)h * 128 + part;
#pragma unroll
                for (int reg = 0; reg < 4; ++reg)
                    qk[(size_t)(row_b + reg) * QK_STRIDE + base] = f2bf(v[reg] * sc);
            } else {                           // V -> vT[bh][i][s], 8B packed
                int i  = part - 128;
                int b  = row_b >> 11;
                int s  = row_b & 2047;
                i32x2 pk;
                pk.x = (int)pack2bf(v[0], v[1]);
                pk.y = (int)pack2bf(v[2], v[3]);
                *(i32x2*)&vT[(((size_t)(b * 16 + h)) * 64 + i) * SEQ + s] = pk;
            }
        }
}

// ---------------------------------------------------------------- GEMM2 128x64
// out[4096,1024] = attn @ out_w^T + out_b.  512 blocks = 2/CU exact.
__global__ __launch_bounds__(256, 2)
void gemm2_kernel(const unsigned short* __restrict__ A,
                  const unsigned short* __restrict__ B,
                  const float* __restrict__ bias,
                  float* __restrict__ C, int M, int N, int K) {
    __shared__ __align__(16) unsigned short As[128 * 64];   // 16KB
    __shared__ __align__(16) unsigned short Bs[64 * 64];    //  8KB

    const int tid  = threadIdx.x;
    const int wave = tid >> 6, lane = tid & 63;
    const int quad = lane >> 4, l16 = lane & 15;
    const int row0 = blockIdx.y * 128, col0 = blockIdx.x * 64;
    const int wr = wave * 32;

    f32x4 acc[2][4];
#pragma unroll
    for (int i = 0; i < 2; ++i)
#pragma unroll
        for (int j = 0; j < 4; ++j) acc[i][j] = (f32x4){0.f, 0.f, 0.f, 0.f};

    const int nkt = K >> 6;
    for (int kt = 0; kt < nkt; ++kt) {
        const int k0 = kt << 6;
#pragma unroll
        for (int i = 0; i < 4; ++i) {
            int p = i * 256 + tid;
            int r = p >> 3;
            int kc = (p & 7) ^ (r & 7);
            load_lds16(A + (size_t)(row0 + r) * K + k0 + kc * 8, &As[p * 8]);
        }
#pragma unroll
        for (int i = 0; i < 2; ++i) {
            int p = i * 256 + tid;
            int r = p >> 3;
            int kc = (p & 7) ^ (r & 7);
            load_lds16(B + (size_t)(col0 + r) * K + k0 + kc * 8, &Bs[p * 8]);
        }
        __syncthreads();

#pragma unroll
        for (int ks = 0; ks < 2; ++ks) {
            bf16x8 af[2], bfr[4];
#pragma unroll
            for (int rb = 0; rb < 2; ++rb) {
                int r_l  = wr + rb * 16 + l16;
                int phys = (ks * 4 + quad) ^ (l16 & 7);
                af[rb] = lds_read8(&As[r_l * 64 + phys * 8]);
            }
#pragma unroll
            for (int cb = 0; cb < 4; ++cb) {
                int r_l  = cb * 16 + l16;
                int phys = (ks * 4 + quad) ^ (l16 & 7);
                bfr[cb] = lds_read8(&Bs[r_l * 64 + phys * 8]);
            }
#pragma unroll
            for (int rb = 0; rb < 2; ++rb)
#pragma unroll
                for (int cb = 0; cb < 4; ++cb)
                    acc[rb][cb] = mfma16(af[rb], bfr[cb], acc[rb][cb]);
        }
        __syncthreads();
    }

#pragma unroll
    for (int rb = 0; rb < 2; ++rb)
#pragma unroll
        for (int cb = 0; cb < 4; ++cb) {
            int col = col0 + cb * 16 + l16;
            float bv = bias[col];
#pragma unroll
            for (int reg = 0; reg < 4; ++reg) {
                int row = row0 + wr + rb * 16 + quad * 4 + reg;
                C[(size_t)row * N + col] = acc[rb][cb][reg] + bv;
            }
        }
}

// ---------------------------------------------------------------- attention
// Block: one (b,h), 128 queries, 256 threads (4 waves x 32 queries, 2 groups).
// 64-key tiles, K/V double-buffered, one barrier/tile with prefetch.
// Every K/V b128 read feeds 2 MFMAs (one per query group) -> halved LDS/FLOP.
// Denominator via MFMA(P, ones). LDS: Ks 16K + Vs 16K + Ps 16K = 48KB.
__global__ __launch_bounds__(256, 2)
void attn_kernel(const unsigned short* __restrict__ qk,
                 const unsigned short* __restrict__ vT,
                 unsigned short* __restrict__ attn) {
    __shared__ __align__(16) unsigned short lds[24576];
    // shorts: Ks[buf] @ buf*4096 ; Vs[buf] @ 8192+buf*4096 ;
    //         Ps @ 16384 + wave*2048 + g*1024   (per wave, per query group)

    const int tid  = threadIdx.x;
    const int wave = tid >> 6, lane = tid & 63;
    const int quad = lane >> 4, l16 = lane & 15;
    const int bh = blockIdx.y;
    const int b = bh >> 4, h = bh & 15;
    const int q0 = blockIdx.x * 128;
    const size_t rowbase = (size_t)b * SEQ;
    const int sw3 = l16 & 7;

    const unsigned short* kroot = qk + rowbase * QK_STRIDE + h * 128 + 64;
    const unsigned short* vroot = vT + (size_t)bh * 64 * SEQ;

    // staging: per thread 2 chunks each for K and V (p = i*256+tid in 0..511)
    int srow[2], scol[2];
#pragma unroll
    for (int i = 0; i < 2; ++i) {
        int p = i * 256 + tid;
        srow[i] = p >> 3;
        scol[i] = ((p & 7) ^ (srow[i] & 7)) * 8;
    }

    // fragment read offsets (shorts, within a 4096-short K/V buffer)
    const int fO0 = l16 * 64 + ((quad ^ sw3) * 8);        // k-chunks 0..3
    const int fO1 = l16 * 64 + (((4 + quad) ^ sw3) * 8);  // k-chunks 4..7
    // P write/read offsets per group
    int pwO[2][4], prO[2][2];
#pragma unroll
    for (int g = 0; g < 2; ++g) {
        int base = 16384 + wave * 2048 + g * 1024;
#pragma unroll
        for (int c4 = 0; c4 < 4; ++c4)
            pwO[g][c4] = base + l16 * 64
                       + (((c4 * 2 + (quad >> 1)) ^ sw3) * 8) + (quad & 1) * 4;
        prO[g][0] = base + fO0;
        prO[g][1] = base + fO1;
    }

    // all-ones B fragment (bf16 1.0) for the denominator MFMA
    union { short s[8]; bf16x8 v; } uon;
#pragma unroll
    for (int j = 0; j < 8; ++j) uon.s[j] = (short)0x3F80;
    const bf16x8 onesb = uon.v;

    // Q fragments: group g queries q0+wave*32+g*16+l16 (B-operand n=l16)
    bf16x8 qf[2][2];
#pragma unroll
    for (int g = 0; g < 2; ++g)
#pragma unroll
        for (int ks = 0; ks < 2; ++ks) {
            const unsigned short* p =
                qk + (rowbase + q0 + wave * 32 + g * 16 + l16) * QK_STRIDE
                   + h * 128 + ks * 32 + quad * 8;
            union { i32x4 i; bf16x8 b; } u;
            u.i = *(const i32x4*)p;
            qf[g][ks] = u.b;
        }

    f32x4 o[2][4];
#pragma unroll
    for (int g = 0; g < 2; ++g)
#pragma unroll
        for (int ib = 0; ib < 4; ++ib) o[g][ib] = (f32x4){0.f, 0.f, 0.f, 0.f};
    f32x4 lacc[2];
    lacc[0] = (f32x4){0.f, 0.f, 0.f, 0.f};
    lacc[1] = (f32x4){0.f, 0.f, 0.f, 0.f};

    // prologue: stage tile 0 into buf 0
#pragma unroll
    for (int i = 0; i < 2; ++i) {
        int p = i * 256 + tid;
        load_lds16(kroot + srow[i] * QK_STRIDE + scol[i], &lds[p * 8]);
    }
#pragma unroll
    for (int i = 0; i < 2; ++i) {
        int p = i * 256 + tid;
        load_lds16(vroot + srow[i] * SEQ + scol[i], &lds[8192 + p * 8]);
    }

    for (int kt = 0; kt < SEQ / 64; ++kt) {
        const int cur = kt & 1;
        __syncthreads();   // drains stage(kt) (a full compute phase old)

        if (kt < SEQ / 64 - 1) {      // prefetch tile kt+1 into other buffer
            const int kb = (kt + 1) * 64;
            const int nb = (cur ^ 1) * 4096;
#pragma unroll
            for (int i = 0; i < 2; ++i) {
                int p = i * 256 + tid;
                load_lds16(kroot + (size_t)(kb + srow[i]) * QK_STRIDE + scol[i],
                           &lds[nb + p * 8]);
            }
#pragma unroll
            for (int i = 0; i < 2; ++i) {
                int p = i * 256 + tid;
                load_lds16(vroot + srow[i] * SEQ + kb + scol[i],
                           &lds[8192 + nb + p * 8]);
            }
        }

        const unsigned short* ksb = &lds[cur * 4096];
        const unsigned short* vsb = &lds[8192 + cur * 4096];

        // ---- S^T = K·Q^T ; each K-frag read feeds both query groups
        f32x4 s[2][4];
#pragma unroll
        for (int g = 0; g < 2; ++g)
#pragma unroll
            for (int cb = 0; cb < 4; ++cb) s[g][cb] = (f32x4){0.f, 0.f, 0.f, 0.f};
#pragma unroll
        for (int cb = 0; cb < 4; ++cb) {
            bf16x8 kf = lds_read8(ksb + fO0 + cb * 1024);
            s[0][cb] = mfma16(kf, qf[0][0], s[0][cb]);
            s[1][cb] = mfma16(kf, qf[1][0], s[1][cb]);
        }
#pragma unroll
        for (int cb = 0; cb < 4; ++cb) {
            bf16x8 kf = lds_read8(ksb + fO1 + cb * 1024);
            s[0][cb] = mfma16(kf, qf[0][1], s[0][cb]);
            s[1][cb] = mfma16(kf, qf[1][1], s[1][cb]);
        }

        // ---- P = exp2(raw) -> bf16 -> LDS (both groups)
#pragma unroll
        for (int g = 0; g < 2; ++g)
#pragma unroll
            for (int c4 = 0; c4 < 4; ++c4) {
                i32x2 pk;
                pk.x = (int)pack2bf(EXP2F(s[g][c4][0]), EXP2F(s[g][c4][1]));
                pk.y = (int)pack2bf(EXP2F(s[g][c4][2]), EXP2F(s[g][c4][3]));
                *(i32x2*)&lds[pwO[g][c4]] = pk;
            }
        __asm__ volatile("s_waitcnt lgkmcnt(0)" ::: "memory");
        {
            bf16x8 pf[2][2];
#pragma unroll
            for (int g = 0; g < 2; ++g) {
                pf[g][0] = lds_read8(&lds[prO[g][0]]);
                pf[g][1] = lds_read8(&lds[prO[g][1]]);
                lacc[g] = mfma16(pf[g][0], onesb, lacc[g]);
                lacc[g] = mfma16(pf[g][1], onesb, lacc[g]);
            }
#pragma unroll
            for (int ib = 0; ib < 4; ++ib) {
                bf16x8 vf = lds_read8(vsb + fO0 + ib * 1024);
                o[0][ib] = mfma16(pf[0][0], vf, o[0][ib]);
                o[1][ib] = mfma16(pf[1][0], vf, o[1][ib]);
            }
#pragma unroll
            for (int ib = 0; ib < 4; ++ib) {
                bf16x8 vf = lds_read8(vsb + fO1 + ib * 1024);
                o[0][ib] = mfma16(pf[0][1], vf, o[0][ib]);
                o[1][ib] = mfma16(pf[1][1], vf, o[1][ib]);
            }
        }
    }

    // ---- normalize, write attn[token][h*64+i] (bf16). O rows = quad*4+r;
    //      lacc rows are the same queries -> no shuffle needed.
#pragma unroll
    for (int g = 0; g < 2; ++g) {
        float il[4];
#pragma unroll
        for (int r = 0; r < 4; ++r) il[r] = 1.0f / lacc[g][r];
#pragma unroll
        for (int ib = 0; ib < 4; ++ib)
#pragma unroll
            for (int r = 0; r < 4; ++r) {
                int t = q0 + wave * 32 + g * 16 + quad * 4 + r;
                attn[(rowbase + t) * E_DIM + h * 64 + ib * 16 + l16] =
                    f2bf(o[g][ib][r] * il[r]);
            }
    }
}

// ---------------------------------------------------------------- launch
extern "C" void kernel_launch(void* const* d_in, const int* in_sizes, int n_in,
                              void* d_out, int out_size, void* d_ws, size_t ws_size,
                              hipStream_t stream) {
    const float* x     = (const float*)d_in[0];   // [2,2048,1024]
    const float* qkv_w = (const float*)d_in[1];   // [3072,1024]
    const float* qkv_b = (const float*)d_in[2];   // [3072]
    const float* out_w = (const float*)d_in[3];   // [1024,1024]
    const float* out_b = (const float*)d_in[4];   // [1024]

    char* ws = (char*)d_ws;
    unsigned short* xb   = (unsigned short*)(ws);               //  8 MB
    unsigned short* wqkv = (unsigned short*)(ws + 8388608);     //  6 MB
    unsigned short* wout = (unsigned short*)(ws + 14680064);    //  2 MB
    unsigned short* qk   = (unsigned short*)(ws + 16777216);    // 16 MB [4096][2048]
    unsigned short* attn = (unsigned short*)(ws + 33554432);    //  8 MB
    unsigned short* vT   = (unsigned short*)(ws + 41943040);    //  8 MB [32][64][2048]
    // total 48 MB

    // fused casts: x (1048576 f32x4), qkv_w (786432), out_w (262144)
    cast3_kernel<<<8192, 256, 0, stream>>>(x, xb, 1048576,
                                           qkv_w, wqkv, 786432,
                                           out_w, wout);

    // QKV projection with fused routing: Q,K -> qk (Q scaled); V -> vT
    gemm_qkv_kernel<<<dim3(24, 32), 256, 0, stream>>>(
        xb, wqkv, qkv_b, qk, vT, E_DIM);

    // flash attention -> attn [4096, 1024] bf16 (128q/256thr, 2 blocks/CU)
    attn_kernel<<<dim3(16, 32), 256, 0, stream>>>(qk, vT, attn);

    // out = attn @ out_w^T + out_b   [4096, 1024] fp32 (128x64 tiles, 512 blocks)
    gemm2_kernel<<<dim3(16, 32), 256, 0, stream>>>(
        attn, wout, out_b, (float*)d_out, TOK, E_DIM, E_DIM);
}

// Round 11
// 184.875 us; speedup vs baseline: 1.0320x; 1.0320x over previous
//
#include <hip/hip_runtime.h>
#include <hip/hip_bf16.h>

// MultiHeadAttention: B=2, S=2048, E=1024, H=16, d=64
// bf16 MFMA (16x16x32) everywhere; fp32 softmax.
// R11: P LDS round-trip replaced by v_permlane{16,32}_swap register
// transpose (C-layout S^T -> PV B-operand); PV operand order swapped so
// O comes out lane=query / regs=4 consecutive dims (8B packed stores,
// scalar denominator). Ps LDS deleted (32KB total). Rest = R10.

#define E_DIM   1024
#define NHEADS  16
#define HDIM    64
#define SEQ     2048
#define TOK     4096          // B*S
#define QKV_DIM 3072
#define QK_STRIDE 2048        // compacted Q|K per-token row
#define QSCALE_F 0.18033688011112042f   // 0.125 * log2(e)

typedef __attribute__((ext_vector_type(8))) short bf16x8;   // 8 bf16 = 4 VGPRs
typedef __attribute__((ext_vector_type(4))) float f32x4;
typedef __attribute__((ext_vector_type(4))) int   i32x4;
typedef __attribute__((ext_vector_type(2))) int   i32x2;
typedef __attribute__((ext_vector_type(2))) unsigned u32x2;
typedef __attribute__((ext_vector_type(2))) __bf16 bf16x2_t;

#if __has_builtin(__builtin_amdgcn_exp2f)
#define EXP2F(x) __builtin_amdgcn_exp2f(x)
#else
#define EXP2F(x) exp2f(x)
#endif

__device__ __forceinline__ unsigned pack2bf(float a, float b) {
#if __has_builtin(__builtin_amdgcn_cvt_pk_bf16_f32)
    union { bf16x2_t v; unsigned u; } u;
    u.v = __builtin_amdgcn_cvt_pk_bf16_f32(a, b);
    return u.u;
#else
    union { float f; unsigned u; } ua, ub; ua.f = a; ub.f = b;
    unsigned ra = ua.u + 0x7FFF + ((ua.u >> 16) & 1);
    unsigned rb = ub.u + 0x7FFF + ((ub.u >> 16) & 1);
    return (ra >> 16) | (rb & 0xFFFF0000u);
#endif
}

__device__ __forceinline__ unsigned short f2bf(float x) {   // 1 VALU op
    return (unsigned short)(pack2bf(x, x) & 0xFFFFu);
}

// swap A.hi(32 lanes) <-> B.lo : A'=[A.lo,B.lo], B'=[A.hi,B.hi]
__device__ __forceinline__ void pl32swap(unsigned& a, unsigned& b) {
#if __has_builtin(__builtin_amdgcn_permlane32_swap)
    u32x2 t = __builtin_amdgcn_permlane32_swap(a, b, false, false);
    a = t.x; b = t.y;
#else
    int lane = (int)(threadIdx.x & 63);
    unsigned bl = (unsigned)__shfl((int)b, lane - 32);
    unsigned ah = (unsigned)__shfl((int)a, lane + 32);
    unsigned na = (lane < 32) ? a : bl;
    unsigned nb = (lane < 32) ? ah : b;
    a = na; b = nb;
#endif
}

// swap odd 16-rows of A <-> even 16-rows of B:
// A'=[A.r0,B.r0,A.r2,B.r2], B'=[A.r1,B.r1,A.r3,B.r3]
__device__ __forceinline__ void pl16swap(unsigned& a, unsigned& b) {
#if __has_builtin(__builtin_amdgcn_permlane16_swap)
    u32x2 t = __builtin_amdgcn_permlane16_swap(a, b, false, false);
    a = t.x; b = t.y;
#else
    int lane = (int)(threadIdx.x & 63);
    int row  = (lane >> 4) & 3;
    unsigned bd = (unsigned)__shfl((int)b, lane - 16);
    unsigned au = (unsigned)__shfl((int)a, lane + 16);
    unsigned na = (row & 1) ? bd : a;
    unsigned nb = (row & 1) ? b : au;
    a = na; b = nb;
#endif
}

__device__ __forceinline__ void load_lds16(const void* g, void* l) {
    __builtin_amdgcn_global_load_lds(
        (const __attribute__((address_space(1))) void*)g,
        (__attribute__((address_space(3))) void*)l, 16, 0, 0);
}

__device__ __forceinline__ bf16x8 lds_read8(const unsigned short* p) {
    union { i32x4 i; bf16x8 b; } u;
    u.i = *(const i32x4*)p;   // ds_read_b128
    return u.b;
}

__device__ __forceinline__ f32x4 mfma16(bf16x8 a, bf16x8 b, f32x4 c) {
    return __builtin_amdgcn_mfma_f32_16x16x32_bf16(a, b, c, 0, 0, 0);
}

// ---------------------------------------------------------------- fused casts
__global__ void cast3_kernel(const float* __restrict__ a, unsigned short* __restrict__ oa, int na4,
                             const float* __restrict__ b, unsigned short* __restrict__ ob, int nb4,
                             const float* __restrict__ c, unsigned short* __restrict__ oc) {
    int i = blockIdx.x * blockDim.x + threadIdx.x;
    const float* src; unsigned short* dst; int j;
    if (i < na4)            { src = a; dst = oa; j = i; }
    else if (i < na4 + nb4) { src = b; dst = ob; j = i - na4; }
    else                    { src = c; dst = oc; j = i - na4 - nb4; }
    f32x4 v = ((const f32x4*)src)[j];
    union { i32x2 i2; unsigned u[2]; } o;
    o.u[0] = pack2bf(v.x, v.y);
    o.u[1] = pack2bf(v.z, v.w);
    ((i32x2*)dst)[j] = o.i2;
}

// ---------------------------------------------------------------- GEMM1 (QKV)
__global__ __launch_bounds__(256, 3)
void gemm_qkv_kernel(const unsigned short* __restrict__ A,
                     const unsigned short* __restrict__ B,
                     const float* __restrict__ bias,
                     unsigned short* __restrict__ qk,
                     unsigned short* __restrict__ vT,
                     int K) {
    __shared__ __align__(16) unsigned short As[128 * 64];
    __shared__ __align__(16) unsigned short Bs[128 * 64];

    const int tid  = threadIdx.x;
    const int wave = tid >> 6, lane = tid & 63;
    const int quad = lane >> 4, l16 = lane & 15;
    const int row0 = blockIdx.y * 128, col0 = blockIdx.x * 128;
    const int wr = (wave >> 1) * 64, wc = (wave & 1) * 64;

    f32x4 acc[4][4];
#pragma unroll
    for (int i = 0; i < 4; ++i)
#pragma unroll
        for (int j = 0; j < 4; ++j) acc[i][j] = (f32x4){0.f, 0.f, 0.f, 0.f};

    const int nkt = K >> 6;
    for (int kt = 0; kt < nkt; ++kt) {
        const int k0 = kt << 6;
#pragma unroll
        for (int i = 0; i < 4; ++i) {
            int p = i * 256 + tid;
            int r = p >> 3;
            int kc = (p & 7) ^ (r & 7);
            load_lds16(A + (size_t)(row0 + r) * K + k0 + kc * 8, &As[p * 8]);
        }
#pragma unroll
        for (int i = 0; i < 4; ++i) {
            int p = i * 256 + tid;
            int r = p >> 3;
            int kc = (p & 7) ^ (r & 7);
            load_lds16(B + (size_t)(col0 + r) * K + k0 + kc * 8, &Bs[p * 8]);
        }
        __syncthreads();

#pragma unroll
        for (int ks = 0; ks < 2; ++ks) {
            bf16x8 af[4], bfr[4];
#pragma unroll
            for (int rb = 0; rb < 4; ++rb) {
                int r_l  = wr + rb * 16 + l16;
                int phys = (ks * 4 + quad) ^ (l16 & 7);
                af[rb] = lds_read8(&As[r_l * 64 + phys * 8]);
            }
#pragma unroll
            for (int cb = 0; cb < 4; ++cb) {
                int r_l  = wc + cb * 16 + l16;
                int phys = (ks * 4 + quad) ^ (l16 & 7);
                bfr[cb] = lds_read8(&Bs[r_l * 64 + phys * 8]);
            }
#pragma unroll
            for (int rb = 0; rb < 4; ++rb)
#pragma unroll
                for (int cb = 0; cb < 4; ++cb)
                    acc[rb][cb] = mfma16(af[rb], bfr[cb], acc[rb][cb]);
        }
        __syncthreads();
    }

    // epilogue: C row = quad*4+reg, col = l16 (m89/m91 layout)
#pragma unroll
    for (int rb = 0; rb < 4; ++rb)
#pragma unroll
        for (int cb = 0; cb < 4; ++cb) {
            int col = col0 + wc + cb * 16 + l16;
            int h    = col / 192;
            int part = col - h * 192;
            float bv = bias[col];
            int row_b = row0 + wr + rb * 16 + quad * 4;
            float v[4];
#pragma unroll
            for (int reg = 0; reg < 4; ++reg) v[reg] = acc[rb][cb][reg] + bv;
            if (part < 128) {                  // Q or K -> qk row-major
                float sc = (part < 64) ? QSCALE_F : 1.0f;
                size_t base = (size_t)h * 128 + part;
#pragma unroll
                for (int reg = 0; reg < 4; ++reg)
                    qk[(size_t)(row_b + reg) * QK_STRIDE + base] = f2bf(v[reg] * sc);
            } else {                           // V -> vT[bh][i][s], 8B packed
                int i  = part - 128;
                int b  = row_b >> 11;
                int s  = row_b & 2047;
                i32x2 pk;
                pk.x = (int)pack2bf(v[0], v[1]);
                pk.y = (int)pack2bf(v[2], v[3]);
                *(i32x2*)&vT[(((size_t)(b * 16 + h)) * 64 + i) * SEQ + s] = pk;
            }
        }
}

// ---------------------------------------------------------------- GEMM2 128x64
__global__ __launch_bounds__(256, 2)
void gemm2_kernel(const unsigned short* __restrict__ A,
                  const unsigned short* __restrict__ B,
                  const float* __restrict__ bias,
                  float* __restrict__ C, int M, int N, int K) {
    __shared__ __align__(16) unsigned short As[128 * 64];   // 16KB
    __shared__ __align__(16) unsigned short Bs[64 * 64];    //  8KB

    const int tid  = threadIdx.x;
    const int wave = tid >> 6, lane = tid & 63;
    const int quad = lane >> 4, l16 = lane & 15;
    const int row0 = blockIdx.y * 128, col0 = blockIdx.x * 64;
    const int wr = wave * 32;

    f32x4 acc[2][4];
#pragma unroll
    for (int i = 0; i < 2; ++i)
#pragma unroll
        for (int j = 0; j < 4; ++j) acc[i][j] = (f32x4){0.f, 0.f, 0.f, 0.f};

    const int nkt = K >> 6;
    for (int kt = 0; kt < nkt; ++kt) {
        const int k0 = kt << 6;
#pragma unroll
        for (int i = 0; i < 4; ++i) {
            int p = i * 256 + tid;
            int r = p >> 3;
            int kc = (p & 7) ^ (r & 7);
            load_lds16(A + (size_t)(row0 + r) * K + k0 + kc * 8, &As[p * 8]);
        }
#pragma unroll
        for (int i = 0; i < 2; ++i) {
            int p = i * 256 + tid;
            int r = p >> 3;
            int kc = (p & 7) ^ (r & 7);
            load_lds16(B + (size_t)(col0 + r) * K + k0 + kc * 8, &Bs[p * 8]);
        }
        __syncthreads();

#pragma unroll
        for (int ks = 0; ks < 2; ++ks) {
            bf16x8 af[2], bfr[4];
#pragma unroll
            for (int rb = 0; rb < 2; ++rb) {
                int r_l  = wr + rb * 16 + l16;
                int phys = (ks * 4 + quad) ^ (l16 & 7);
                af[rb] = lds_read8(&As[r_l * 64 + phys * 8]);
            }
#pragma unroll
            for (int cb = 0; cb < 4; ++cb) {
                int r_l  = cb * 16 + l16;
                int phys = (ks * 4 + quad) ^ (l16 & 7);
                bfr[cb] = lds_read8(&Bs[r_l * 64 + phys * 8]);
            }
#pragma unroll
            for (int rb = 0; rb < 2; ++rb)
#pragma unroll
                for (int cb = 0; cb < 4; ++cb)
                    acc[rb][cb] = mfma16(af[rb], bfr[cb], acc[rb][cb]);
        }
        __syncthreads();
    }

#pragma unroll
    for (int rb = 0; rb < 2; ++rb)
#pragma unroll
        for (int cb = 0; cb < 4; ++cb) {
            int col = col0 + cb * 16 + l16;
            float bv = bias[col];
#pragma unroll
            for (int reg = 0; reg < 4; ++reg) {
                int row = row0 + wr + rb * 16 + quad * 4 + reg;
                C[(size_t)row * N + col] = acc[rb][cb][reg] + bv;
            }
        }
}

// ---------------------------------------------------------------- attention
// Block: one (b,h), 128 queries, 256 threads (4 waves x 32 queries, 2 groups).
// 64-key tiles, K/V double-buffered, one barrier/tile with prefetch.
// S^T (C-layout) -> PV B-operand via permlane swaps (no P LDS round-trip).
// PV: A=V-fragment, B=P^T -> O lane=query, regs=4 consecutive i dims.
// LDS: Ks[2] 16K + Vs[2] 16K = 32KB.
__global__ __launch_bounds__(256, 2)
void attn_kernel(const unsigned short* __restrict__ qk,
                 const unsigned short* __restrict__ vT,
                 unsigned short* __restrict__ attn) {
    __shared__ __align__(16) unsigned short lds[16384];
    // shorts: Ks[buf] @ buf*4096 ; Vs[buf] @ 8192+buf*4096

    const int tid  = threadIdx.x;
    const int wave = tid >> 6, lane = tid & 63;
    const int quad = lane >> 4, l16 = lane & 15;
    const int bh = blockIdx.y;
    const int b = bh >> 4, h = bh & 15;
    const int q0 = blockIdx.x * 128;
    const size_t rowbase = (size_t)b * SEQ;
    const int sw3 = l16 & 7;

    const unsigned short* kroot = qk + rowbase * QK_STRIDE + h * 128 + 64;
    const unsigned short* vroot = vT + (size_t)bh * 64 * SEQ;

    int srow[2], scol[2];
#pragma unroll
    for (int i = 0; i < 2; ++i) {
        int p = i * 256 + tid;
        srow[i] = p >> 3;
        scol[i] = ((p & 7) ^ (srow[i] & 7)) * 8;
    }

    // fragment read offsets (shorts, within a 4096-short K/V buffer)
    const int fO0 = l16 * 64 + ((quad ^ sw3) * 8);        // k-chunks 0..3
    const int fO1 = l16 * 64 + (((4 + quad) ^ sw3) * 8);  // k-chunks 4..7

    // all-ones A fragment (bf16 1.0) for the denominator MFMA
    union { short s[8]; bf16x8 v; } uon;
#pragma unroll
    for (int j = 0; j < 8; ++j) uon.s[j] = (short)0x3F80;
    const bf16x8 onesb = uon.v;

    // Q fragments: group g queries q0+wave*32+g*16+l16 (B-operand n=l16)
    bf16x8 qf[2][2];
#pragma unroll
    for (int g = 0; g < 2; ++g)
#pragma unroll
        for (int ks = 0; ks < 2; ++ks) {
            const unsigned short* p =
                qk + (rowbase + q0 + wave * 32 + g * 16 + l16) * QK_STRIDE
                   + h * 128 + ks * 32 + quad * 8;
            union { i32x4 i; bf16x8 b; } u;
            u.i = *(const i32x4*)p;
            qf[g][ks] = u.b;
        }

    f32x4 o[2][4];      // o[g][ib]: lane=query l16, reg r -> dim ib*16+quad*4+r
#pragma unroll
    for (int g = 0; g < 2; ++g)
#pragma unroll
        for (int ib = 0; ib < 4; ++ib) o[g][ib] = (f32x4){0.f, 0.f, 0.f, 0.f};
    f32x4 lacc[2];
    lacc[0] = (f32x4){0.f, 0.f, 0.f, 0.f};
    lacc[1] = (f32x4){0.f, 0.f, 0.f, 0.f};

    // prologue: stage tile 0 into buf 0
#pragma unroll
    for (int i = 0; i < 2; ++i) {
        int p = i * 256 + tid;
        load_lds16(kroot + srow[i] * QK_STRIDE + scol[i], &lds[p * 8]);
    }
#pragma unroll
    for (int i = 0; i < 2; ++i) {
        int p = i * 256 + tid;
        load_lds16(vroot + srow[i] * SEQ + scol[i], &lds[8192 + p * 8]);
    }

    for (int kt = 0; kt < SEQ / 64; ++kt) {
        const int cur = kt & 1;
        __syncthreads();   // drains stage(kt) (a full compute phase old)

        if (kt < SEQ / 64 - 1) {      // prefetch tile kt+1 into other buffer
            const int kb = (kt + 1) * 64;
            const int nb = (cur ^ 1) * 4096;
#pragma unroll
            for (int i = 0; i < 2; ++i) {
                int p = i * 256 + tid;
                load_lds16(kroot + (size_t)(kb + srow[i]) * QK_STRIDE + scol[i],
                           &lds[nb + p * 8]);
            }
#pragma unroll
            for (int i = 0; i < 2; ++i) {
                int p = i * 256 + tid;
                load_lds16(vroot + srow[i] * SEQ + kb + scol[i],
                           &lds[8192 + nb + p * 8]);
            }
        }

        const unsigned short* ksb = &lds[cur * 4096];
        const unsigned short* vsb = &lds[8192 + cur * 4096];

        // ---- S^T = K·Q^T ; each K-frag read feeds both query groups
        f32x4 s[2][4];
#pragma unroll
        for (int g = 0; g < 2; ++g)
#pragma unroll
            for (int cb = 0; cb < 4; ++cb) s[g][cb] = (f32x4){0.f, 0.f, 0.f, 0.f};
#pragma unroll
        for (int cb = 0; cb < 4; ++cb) {
            bf16x8 kf = lds_read8(ksb + fO0 + cb * 1024);
            s[0][cb] = mfma16(kf, qf[0][0], s[0][cb]);
            s[1][cb] = mfma16(kf, qf[1][0], s[1][cb]);
        }
#pragma unroll
        for (int cb = 0; cb < 4; ++cb) {
            bf16x8 kf = lds_read8(ksb + fO1 + cb * 1024);
            s[0][cb] = mfma16(kf, qf[0][1], s[0][cb]);
            s[1][cb] = mfma16(kf, qf[1][1], s[1][cb]);
        }

        // ---- P = exp2(raw), pack, register-transpose to B-operand, PV
#pragma unroll
        for (int ks2 = 0; ks2 < 2; ++ks2) {
            const int c0 = ks2 * 2, c1 = ks2 * 2 + 1;
            bf16x8 pT[2];
#pragma unroll
            for (int g = 0; g < 2; ++g) {
                unsigned x0a = pack2bf(EXP2F(s[g][c0][0]), EXP2F(s[g][c0][1]));
                unsigned x1a = pack2bf(EXP2F(s[g][c0][2]), EXP2F(s[g][c0][3]));
                unsigned x0b = pack2bf(EXP2F(s[g][c1][0]), EXP2F(s[g][c1][1]));
                unsigned x1b = pack2bf(EXP2F(s[g][c1][2]), EXP2F(s[g][c1][3]));
                pl32swap(x0a, x0b);           // x0a=[c0.qs01|c1.qs01] x0b=[c0.qs23|c1.qs23]
                pl16swap(x0a, x0b);           // x0a=v0, x0b=v2
                pl32swap(x1a, x1b);
                pl16swap(x1a, x1b);           // x1a=v1, x1b=v3
                union { unsigned u[4]; bf16x8 v; } r;
                r.u[0] = x0a; r.u[1] = x1a; r.u[2] = x0b; r.u[3] = x1b;
                pT[g] = r.v;
            }
            lacc[0] = mfma16(onesb, pT[0], lacc[0]);   // denom += sum_k P
            lacc[1] = mfma16(onesb, pT[1], lacc[1]);
            const int fO = ks2 ? fO1 : fO0;
#pragma unroll
            for (int ib = 0; ib < 4; ++ib) {
                bf16x8 vf = lds_read8(vsb + fO + ib * 1024);  // A: m=i, k=keys
                o[0][ib] = mfma16(vf, pT[0], o[0][ib]);
                o[1][ib] = mfma16(vf, pT[1], o[1][ib]);
            }
        }
    }

    // ---- normalize, write attn[token][h*64+i] (bf16).
    // o[g][ib] reg r -> dim ib*16+quad*4+r of query l16 -> 8B packed stores.
#pragma unroll
    for (int g = 0; g < 2; ++g) {
        float il = 1.0f / lacc[g][0];
        int t = q0 + wave * 32 + g * 16 + l16;
        unsigned short* orow = attn + (rowbase + t) * E_DIM + h * 64 + quad * 4;
#pragma unroll
        for (int ib = 0; ib < 4; ++ib) {
            i32x2 pk;
            pk.x = (int)pack2bf(o[g][ib][0] * il, o[g][ib][1] * il);
            pk.y = (int)pack2bf(o[g][ib][2] * il, o[g][ib][3] * il);
            *(i32x2*)(orow + ib * 16) = pk;
        }
    }
}

// ---------------------------------------------------------------- launch
extern "C" void kernel_launch(void* const* d_in, const int* in_sizes, int n_in,
                              void* d_out, int out_size, void* d_ws, size_t ws_size,
                              hipStream_t stream) {
    const float* x     = (const float*)d_in[0];   // [2,2048,1024]
    const float* qkv_w = (const float*)d_in[1];   // [3072,1024]
    const float* qkv_b = (const float*)d_in[2];   // [3072]
    const float* out_w = (const float*)d_in[3];   // [1024,1024]
    const float* out_b = (const float*)d_in[4];   // [1024]

    char* ws = (char*)d_ws;
    unsigned short* xb   = (unsigned short*)(ws);               //  8 MB
    unsigned short* wqkv = (unsigned short*)(ws + 8388608);     //  6 MB
    unsigned short* wout = (unsigned short*)(ws + 14680064);    //  2 MB
    unsigned short* qk   = (unsigned short*)(ws + 16777216);    // 16 MB [4096][2048]
    unsigned short* attn = (unsigned short*)(ws + 33554432);    //  8 MB
    unsigned short* vT   = (unsigned short*)(ws + 41943040);    //  8 MB [32][64][2048]
    // total 48 MB

    // fused casts: x (1048576 f32x4), qkv_w (786432), out_w (262144)
    cast3_kernel<<<8192, 256, 0, stream>>>(x, xb, 1048576,
                                           qkv_w, wqkv, 786432,
                                           out_w, wout);

    // QKV projection with fused routing: Q,K -> qk (Q scaled); V -> vT
    gemm_qkv_kernel<<<dim3(24, 32), 256, 0, stream>>>(
        xb, wqkv, qkv_b, qk, vT, E_DIM);

    // flash attention -> attn [4096, 1024] bf16 (128q/256thr, 2 blocks/CU)
    attn_kernel<<<dim3(16, 32), 256, 0, stream>>>(qk, vT, attn);

    // out = attn @ out_w^T + out_b   [4096, 1024] fp32 (128x64 tiles, 512 blocks)
    gemm2_kernel<<<dim3(16, 32), 256, 0, stream>>>(
        attn, wout, out_b, (float*)d_out, TOK, E_DIM, E_DIM);
}